// Round 14
// baseline (192.569 us; speedup 1.0000x reference)
//
#include <hip/hip_runtime.h>

#define NUSERS 100000
#define NITEMS 50000
#define NV (NUSERS + NITEMS)
#define DIM 64
#define NLAYERS 3
#define PAD 64                         // direct slots per vertex (max degree <= 64, validated r7/r8)
#define BINSHIFT 9
#define BINSZ 512
#define NBINS ((NV + BINSZ - 1) / BINSZ)   // 293
#define EPB 2048                       // edges per scatter block
#define RPB (2 * EPB)                  // records per block region (exact capacity)
#define CSTRIDE (NBINS + 1)            // cnt row stride

typedef _Float16 half2v __attribute__((ext_vector_type(2)));
typedef _Float16 half4v __attribute__((ext_vector_type(4)));
typedef _Float16 half8v __attribute__((ext_vector_type(8)));

// ---------------- stage 1: block-local bin-grouped record emit ----------------
// Each block owns a fixed 4096-record region of binbuf. LDS hist -> LDS scan ->
// LDS-rank write (grouped by bin). Emits its 294-entry offset row to cnt.
// Zero global atomics; all record writes land in the block's private 16 KB.
__global__ void scatter_kernel(const int* __restrict__ tu, const int* __restrict__ ti,
                               int* __restrict__ cnt, unsigned int* __restrict__ binbuf,
                               int E) {
    __shared__ int h[NBINS];
    __shared__ int off[NBINS + 1];
    __shared__ int sh[256];
    int t = threadIdx.x, b = blockIdx.x;
    for (int i = t; i < NBINS; i += 256) h[i] = 0;
    __syncthreads();

    int base = b * EPB;
    int us[8], ws_[8];
    int e0 = base + t * 4;
    int e1 = base + 1024 + t * 4;
    int n0 = min(max(E - e0, 0), 4);
    int n1 = min(max(E - e1, 0), 4);
    if (n0 == 4) {
        int4 u4 = *reinterpret_cast<const int4*>(tu + e0);
        int4 i4 = *reinterpret_cast<const int4*>(ti + e0);
        us[0] = u4.x; us[1] = u4.y; us[2] = u4.z; us[3] = u4.w;
        ws_[0] = NUSERS + i4.x; ws_[1] = NUSERS + i4.y;
        ws_[2] = NUSERS + i4.z; ws_[3] = NUSERS + i4.w;
    } else {
#pragma unroll
        for (int k = 0; k < 4; ++k)
            if (k < n0) { us[k] = tu[e0 + k]; ws_[k] = NUSERS + ti[e0 + k]; }
    }
    if (n1 == 4) {
        int4 u4 = *reinterpret_cast<const int4*>(tu + e1);
        int4 i4 = *reinterpret_cast<const int4*>(ti + e1);
        us[4] = u4.x; us[5] = u4.y; us[6] = u4.z; us[7] = u4.w;
        ws_[4] = NUSERS + i4.x; ws_[5] = NUSERS + i4.y;
        ws_[6] = NUSERS + i4.z; ws_[7] = NUSERS + i4.w;
    } else {
#pragma unroll
        for (int k = 0; k < 4; ++k)
            if (k < n1) { us[4 + k] = tu[e1 + k]; ws_[4 + k] = NUSERS + ti[e1 + k]; }
    }

    // pass A: LDS histogram (static indices only; rule-of-thumb: no runtime array idx)
#pragma unroll
    for (int k = 0; k < 4; ++k)
        if (k < n0) {
            atomicAdd(&h[us[k] >> BINSHIFT], 1);
            atomicAdd(&h[ws_[k] >> BINSHIFT], 1);
        }
#pragma unroll
    for (int k = 0; k < 4; ++k)
        if (k < n1) {
            atomicAdd(&h[us[4 + k] >> BINSHIFT], 1);
            atomicAdd(&h[ws_[4 + k] >> BINSHIFT], 1);
        }
    __syncthreads();

    // LDS exclusive scan over 293 bins (2 bins/thread)
    int i0 = 2 * t, i1 = 2 * t + 1;
    int c0 = (i0 < NBINS) ? h[i0] : 0;
    int c1 = (i1 < NBINS) ? h[i1] : 0;
    int sum2 = c0 + c1;
    sh[t] = sum2;
    __syncthreads();
    for (int d = 1; d < 256; d <<= 1) {
        int x = (t >= d) ? sh[t - d] : 0;
        __syncthreads();
        sh[t] += x;
        __syncthreads();
    }
    int run = sh[t] - sum2;
    if (i0 < NBINS) off[i0] = run;
    if (i1 < NBINS) off[i1] = run + c0;
    if (t == 255) off[NBINS] = sh[255];
    __syncthreads();

    // emit offset row; reset h for rank pass
    for (int i = t; i <= NBINS; i += 256) cnt[(size_t)b * CSTRIDE + i] = off[i];
    for (int i = t; i < NBINS; i += 256) h[i] = 0;
    __syncthreads();

    // pass B: rank + grouped write into private region
    unsigned int* reg = binbuf + (size_t)b * RPB;
#pragma unroll
    for (int k = 0; k < 4; ++k)
        if (k < n0) {
            int u = us[k], w = ws_[k];
            int bu = u >> BINSHIFT, bw = w >> BINSHIFT;
            int r1 = atomicAdd(&h[bu], 1);
            reg[off[bu] + r1] = ((unsigned)(u & (BINSZ - 1)) << 18) | (unsigned)w;
            int r2 = atomicAdd(&h[bw], 1);
            reg[off[bw] + r2] = ((unsigned)(w & (BINSZ - 1)) << 18) | (unsigned)u;
        }
#pragma unroll
    for (int k = 0; k < 4; ++k)
        if (k < n1) {
            int u = us[4 + k], w = ws_[4 + k];
            int bu = u >> BINSHIFT, bw = w >> BINSHIFT;
            int r1 = atomicAdd(&h[bu], 1);
            reg[off[bu] + r1] = ((unsigned)(u & (BINSZ - 1)) << 18) | (unsigned)w;
            int r2 = atomicAdd(&h[bw], 1);
            reg[off[bw] + r2] = ((unsigned)(w & (BINSZ - 1)) << 18) | (unsigned)u;
        }
}

// ---------------- stage 2: per-bin rank + adj fill + deg + fused init ----------------
// One block per bin (512 threads). Thread b walks block b's segment for this bin
// (LDS-atomic vertex ranks, adj writes into the bin's private 128 KB window).
// Then degrees -> rsd in LDS, and the block rescales its own 512 contiguous
// rows users_w/items_w -> f16 Yh (fully coalesced). Block 0 zeroes pad rows.
__global__ void bfill_kernel(const unsigned int* __restrict__ binbuf,
                             const int* __restrict__ cnt,
                             const float* __restrict__ users_w,
                             const float* __restrict__ items_w,
                             int* __restrict__ deg, int* __restrict__ adj,
                             _Float16* __restrict__ Yh, _Float16* __restrict__ Dh,
                             int nblk) {
    __shared__ int c[BINSZ];
    __shared__ float rs[BINSZ];
    int bin = blockIdx.x, t = threadIdx.x;     // blockDim = 512
    c[t] = 0;
    __syncthreads();
    int vbase = bin << BINSHIFT;
    for (int b = t; b < nblk; b += 512) {
        int s = cnt[(size_t)b * CSTRIDE + bin];
        int e = cnt[(size_t)b * CSTRIDE + bin + 1];
        const unsigned int* reg = binbuf + (size_t)b * RPB;
        for (int k = s; k < e; ++k) {
            unsigned rec = reg[k];
            int vloc = rec >> 18;
            int nbr = (int)(rec & 0x3FFFFu);
            int r = atomicAdd(&c[vloc], 1);
            adj[((vbase + vloc) << 6) + r] = nbr << 7;   // byte offset of the row
        }
    }
    __syncthreads();
    {
        int v = vbase + t;
        if (v < NV) {
            deg[v] = c[t];
            rs[t] = rsqrtf(fmaxf((float)c[t], 1.0f));
        }
    }
    __syncthreads();
    // fused init: 32 vertices x 16 float4-chunks per iteration (coalesced)
    int chunk = t & 15;
    int vloc0 = t >> 4;
    for (int it = 0; it < 16; ++it) {
        int vloc = it * 32 + vloc0;
        int v = vbase + vloc;
        if (v < NV) {
            float r = rs[vloc];
            const float4* sp = (v < NUSERS)
                ? reinterpret_cast<const float4*>(users_w) + (size_t)v * 16 + chunk
                : reinterpret_cast<const float4*>(items_w) + (size_t)(v - NUSERS) * 16 + chunk;
            float4 x = *sp;
            half4v hh;
            hh.x = (_Float16)(x.x * r);
            hh.y = (_Float16)(x.y * r);
            hh.z = (_Float16)(x.z * r);
            hh.w = (_Float16)(x.w * r);
            reinterpret_cast<half4v*>(Yh + (size_t)v * DIM)[chunk] = hh;
        }
    }
    if (bin == 0) {
        if (t < 16) reinterpret_cast<half4v*>(Yh + (size_t)NV * DIM)[t] = half4v{};
        else if (t < 32) reinterpret_cast<half4v*>(Dh + (size_t)NV * DIM)[t - 16] = half4v{};
    }
}

// ---------------- gather-reduce propagation (unchanged from r12) ----------------
template <bool FINAL>
__global__ void gather_kernel(const _Float16* __restrict__ Yh, const int* __restrict__ deg,
                              const int* __restrict__ adj,
                              const float* __restrict__ beta_w,
                              void* __restrict__ dst_v, int layer) {
    int wid = (blockIdx.x * blockDim.x + threadIdx.x) >> 6;
    int lane = threadIdx.x & 63;
    if (wid >= NV) return;
    int g = lane >> 3;          // neighbor slot 0..7
    int p = lane & 7;           // dim octet: dims 8p..8p+7
    int s = wid << 6;
    const char* rowb = (const char*)Yh + p * 16;
    const int NVS = NV << 7;    // byte offset of the zero pad row

    // ---- round 1: everything independent issues together ----
    int dg = deg[wid];
    int raw0 = adj[s + g];
    int raw1 = adj[s + 8 + g];
    int raw2 = adj[s + 16 + g];
    int raw3 = adj[s + 24 + g];
    bool isU = wid < NUSERS;
    float bw_ = 0.f;
    half8v hy = {};
    if (isU && g == 0) {
        bw_ = beta_w[wid * NLAYERS + layer];
        hy = *reinterpret_cast<const half8v*>(Yh + (size_t)wid * DIM + p * 8);
    }

    // ---- round 2: row loads gated by degree (wave-uniform) ----
    int o0 = (g < dg) ? raw0 : NVS;
    half8v h0 = *reinterpret_cast<const half8v*>(rowb + (size_t)(unsigned)o0);

    float a[8];
    if (dg > 32) {
        // rare (~0.5%): full f32 path with tail, 3 f32 reduce stages
        int o1 = (8 + g  < dg) ? raw1 : NVS;
        int o2 = (16 + g < dg) ? raw2 : NVS;
        int o3 = (24 + g < dg) ? raw3 : NVS;
        half8v h1 = *reinterpret_cast<const half8v*>(rowb + (size_t)(unsigned)o1);
        half8v h2 = *reinterpret_cast<const half8v*>(rowb + (size_t)(unsigned)o2);
        half8v h3 = *reinterpret_cast<const half8v*>(rowb + (size_t)(unsigned)o3);
        half8v hs = (h0 + h1) + (h2 + h3);
#pragma unroll
        for (int j = 0; j < 8; ++j) a[j] = (float)hs[j];
#pragma unroll
        for (int jb = 0; jb < 4; ++jb) {
            int slotbase = 32 + jb * 8;
            if (slotbase < dg) {
                int ks = slotbase + g;
                int rw = adj[s + ks];
                int oj = (ks < dg) ? rw : NVS;
                half8v hj = *reinterpret_cast<const half8v*>(rowb + (size_t)(unsigned)oj);
#pragma unroll
                for (int j = 0; j < 8; ++j) a[j] += (float)hj[j];
            }
        }
#pragma unroll
        for (int j = 0; j < 8; ++j) a[j] += __shfl_xor(a[j], 8);
    } else {
        half8v hsum;
        if (dg > 16) {
            int o1 = (8 + g  < dg) ? raw1 : NVS;
            int o2 = (16 + g < dg) ? raw2 : NVS;
            int o3 = (24 + g < dg) ? raw3 : NVS;
            half8v h1 = *reinterpret_cast<const half8v*>(rowb + (size_t)(unsigned)o1);
            half8v h2 = *reinterpret_cast<const half8v*>(rowb + (size_t)(unsigned)o2);
            half8v h3 = *reinterpret_cast<const half8v*>(rowb + (size_t)(unsigned)o3);
            hsum = (h0 + h1) + (h2 + h3);
        } else if (dg > 8) {
            int o1 = (8 + g < dg) ? raw1 : NVS;
            half8v h1 = *reinterpret_cast<const half8v*>(rowb + (size_t)(unsigned)o1);
            hsum = h0 + h1;
        } else {
            hsum = h0;
        }
        // stage 1 (xor 8) in packed f16: 4 dword shfl + 4 pk_add
        union { half8v h; int i[4]; } u;
        u.h = hsum;
#pragma unroll
        for (int j = 0; j < 4; ++j) {
            int o = __shfl_xor(u.i[j], 8);
            half2v x = __builtin_bit_cast(half2v, u.i[j]);
            half2v y = __builtin_bit_cast(half2v, o);
            x = x + y;
            u.i[j] = __builtin_bit_cast(int, x);
        }
#pragma unroll
        for (int j = 0; j < 8; ++j) a[j] = (float)u.h[j];
    }

    // stages 2-3 in f32 (lane bits 4,5)
#pragma unroll
    for (int j = 0; j < 8; ++j) a[j] += __shfl_xor(a[j], 16);
#pragma unroll
    for (int j = 0; j < 8; ++j) a[j] += __shfl_xor(a[j], 32);

    if (g == 0) {                      // lanes 0..7 own the output row (octet p)
        float fdg = fmaxf((float)dg, 1.0f);
        float r = rsqrtf(fdg);
        float b = isU ? tanhf(bw_) : 0.f;
        if (!FINAL) {
            float rr = r * r;          // = 1/deg
            half8v o;
#pragma unroll
            for (int j = 0; j < 8; ++j) o[j] = (_Float16)(rr * a[j] + b * (float)hy[j]);
            reinterpret_cast<half8v*>((_Float16*)dst_v + (size_t)wid * DIM)[p] = o;
        } else {
            float c = b * __builtin_sqrtf(fdg);   // b / r
            float4 o0f, o1f;
            o0f.x = r * a[0] + c * (float)hy[0];
            o0f.y = r * a[1] + c * (float)hy[1];
            o0f.z = r * a[2] + c * (float)hy[2];
            o0f.w = r * a[3] + c * (float)hy[3];
            o1f.x = r * a[4] + c * (float)hy[4];
            o1f.y = r * a[5] + c * (float)hy[5];
            o1f.z = r * a[6] + c * (float)hy[6];
            o1f.w = r * a[7] + c * (float)hy[7];
            float4* dp = reinterpret_cast<float4*>((float*)dst_v + (size_t)wid * DIM + p * 8);
            dp[0] = o0f;
            dp[1] = o1f;
        }
    }
}

extern "C" void kernel_launch(void* const* d_in, const int* in_sizes, int n_in,
                              void* d_out, int out_size, void* d_ws, size_t ws_size,
                              hipStream_t stream) {
    const float* users_w = (const float*)d_in[0];
    const float* items_w = (const float*)d_in[1];
    const float* beta_w  = (const float*)d_in[2];
    const int*   tu      = (const int*)d_in[3];
    const int*   ti      = (const int*)d_in[4];
    const int    E       = in_sizes[3];
    float*       out     = (float*)d_out;

    int nblk = (E + EPB - 1) / EPB;

    // ---- workspace layout ----
    char* ws = (char*)d_ws;
    size_t woff = 0;
    auto take = [&](size_t bytes) {
        char* p = ws + woff;
        woff += (bytes + 1023) & ~(size_t)1023;
        return p;
    };
    int*      deg    = (int*)take((size_t)NV * sizeof(int));
    int*      cnt    = (int*)take((size_t)nblk * CSTRIDE * sizeof(int));
    unsigned* binbuf = (unsigned*)take((size_t)nblk * RPB * sizeof(unsigned));
    int*      adj    = (int*)take((size_t)NV * PAD * sizeof(int));
    _Float16* Yh0    = (_Float16*)take((size_t)(NV + 1) * DIM * sizeof(_Float16));

    // f16 intermediate lives inside d_out (38.4 MB f32 holds 19.2 MB f16 + pad row)
    _Float16* Dh = (_Float16*)d_out;

    const int blk = 256;

    // ---- 2-dispatch deterministic CSR build + init (zero global atomics, zero memsets) ----
    scatter_kernel<<<nblk, 256, 0, stream>>>(tu, ti, cnt, binbuf, E);
    bfill_kernel<<<NBINS, 512, 0, stream>>>(binbuf, cnt, users_w, items_w,
                                            deg, adj, Yh0, Dh, nblk);

    // ---- 3 propagation layers: Yh0 -> Dh(d_out) -> Yh0 -> out(f32) ----
    int gblocks = ((size_t)NV * 64 + blk - 1) / blk;

    gather_kernel<false><<<gblocks, blk, 0, stream>>>(Yh0, deg, adj, beta_w, Dh, 0);
    gather_kernel<false><<<gblocks, blk, 0, stream>>>(Dh, deg, adj, beta_w, Yh0, 1);
    gather_kernel<true ><<<gblocks, blk, 0, stream>>>(Yh0, deg, adj, beta_w, out, 2);
}

// Round 15
// 182.555 us; speedup vs baseline: 1.0549x; 1.0549x over previous
//
#include <hip/hip_runtime.h>

#define NUSERS 100000
#define NITEMS 50000
#define NV (NUSERS + NITEMS)
#define DIM 64
#define NLAYERS 3
#define PAD 64                         // direct slots per vertex (max degree <= 64, validated r7/r8)
#define BINSHIFT 9
#define BINSZ 512
#define NBINS ((NV + BINSZ - 1) / BINSZ)   // 293
#define EPB 2048                       // edges per histogram/scatter block

typedef _Float16 half2v __attribute__((ext_vector_type(2)));
typedef _Float16 half4v __attribute__((ext_vector_type(4)));
typedef _Float16 half8v __attribute__((ext_vector_type(8)));

// ---------------- stage 1: per-block bin histogram (LDS atomics only) ----------------
__global__ void hist_kernel(const int* __restrict__ tu, const int* __restrict__ ti,
                            int* __restrict__ cnt, int E) {
    __shared__ int h[NBINS];
    int t = threadIdx.x, b = blockIdx.x;
    for (int i = t; i < NBINS; i += 256) h[i] = 0;
    __syncthreads();
    int base = b * EPB;
#pragma unroll
    for (int j = 0; j < 2; ++j) {
        int e = base + (j * 256 + t) * 4;
        if (e + 4 <= E) {
            int4 u4 = *reinterpret_cast<const int4*>(tu + e);
            int4 i4 = *reinterpret_cast<const int4*>(ti + e);
            atomicAdd(&h[u4.x >> BINSHIFT], 1);
            atomicAdd(&h[u4.y >> BINSHIFT], 1);
            atomicAdd(&h[u4.z >> BINSHIFT], 1);
            atomicAdd(&h[u4.w >> BINSHIFT], 1);
            atomicAdd(&h[(NUSERS + i4.x) >> BINSHIFT], 1);
            atomicAdd(&h[(NUSERS + i4.y) >> BINSHIFT], 1);
            atomicAdd(&h[(NUSERS + i4.z) >> BINSHIFT], 1);
            atomicAdd(&h[(NUSERS + i4.w) >> BINSHIFT], 1);
        } else {
            for (int k = e; k < E && k < e + 4; ++k) {
                atomicAdd(&h[tu[k] >> BINSHIFT], 1);
                atomicAdd(&h[(NUSERS + ti[k]) >> BINSHIFT], 1);
            }
        }
    }
    __syncthreads();
    for (int i = t; i < NBINS; i += 256) cnt[(size_t)b * NBINS + i] = h[i];
}

// ---------------- stage 2: per-bin exclusive scan over blocks (in place) ----------------
__global__ void colscan_kernel(int* __restrict__ cnt, int* __restrict__ bintot, int nblk) {
    __shared__ int sh[256];
    int bin = blockIdx.x, t = threadIdx.x;
    int chunk = (nblk + 255) / 256;            // <=8 for E <= 4M
    int v[8];
    int sum = 0;
    for (int j = 0; j < chunk; ++j) {
        int blk = t * chunk + j;
        v[j] = (blk < nblk) ? cnt[(size_t)blk * NBINS + bin] : 0;
        sum += v[j];
    }
    sh[t] = sum;
    __syncthreads();
    for (int d = 1; d < 256; d <<= 1) {
        int x = (t >= d) ? sh[t - d] : 0;
        __syncthreads();
        sh[t] += x;
        __syncthreads();
    }
    int run = sh[t] - sum;                     // exclusive prefix of this thread's chunk
    for (int j = 0; j < chunk; ++j) {
        int blk = t * chunk + j;
        if (blk < nblk) { cnt[(size_t)blk * NBINS + bin] = run; run += v[j]; }
    }
    if (t == 255) bintot[bin] = sh[255];
}

// ---------------- stage 3: scan of bin totals ----------------
__global__ void binscan_kernel(const int* __restrict__ bintot, int* __restrict__ binstart) {
    __shared__ int sh[512];
    int t = threadIdx.x;
    int v = (t < NBINS) ? bintot[t] : 0;
    sh[t] = v;
    __syncthreads();
    for (int d = 1; d < 512; d <<= 1) {
        int x = (t >= d) ? sh[t - d] : 0;
        __syncthreads();
        sh[t] += x;
        __syncthreads();
    }
    if (t < NBINS) binstart[t] = sh[t] - v;    // exclusive
    if (t == NBINS - 1) binstart[NBINS] = sh[t];
}

// ---------------- stage 4: scatter packed records to bin-contiguous buffer ----------------
// record = (v & 511) << 18 | neighbor_id  (nbr < 150001 fits 18 bits)
__global__ void scatter_kernel(const int* __restrict__ tu, const int* __restrict__ ti,
                               const int* __restrict__ cnt, const int* __restrict__ binstart,
                               unsigned int* __restrict__ binbuf, int E) {
    __shared__ int h[NBINS];
    __shared__ int bbs[NBINS];
    int t = threadIdx.x, b = blockIdx.x;
    for (int i = t; i < NBINS; i += 256) {
        h[i] = 0;
        bbs[i] = cnt[(size_t)b * NBINS + i] + binstart[i];  // block base within global bin
    }
    __syncthreads();
    int base = b * EPB;
#pragma unroll
    for (int j = 0; j < 2; ++j) {
        int e = base + (j * 256 + t) * 4;
        if (e + 4 <= E) {
            int4 u4 = *reinterpret_cast<const int4*>(tu + e);
            int4 i4 = *reinterpret_cast<const int4*>(ti + e);
            int us[4] = {u4.x, u4.y, u4.z, u4.w};
            int is_[4] = {i4.x, i4.y, i4.z, i4.w};
#pragma unroll
            for (int k = 0; k < 4; ++k) {
                int u = us[k];
                int w = NUSERS + is_[k];
                int bu = u >> BINSHIFT, bw = w >> BINSHIFT;
                int r1 = atomicAdd(&h[bu], 1);
                int r2 = atomicAdd(&h[bw], 1);
                binbuf[bbs[bu] + r1] = ((unsigned)(u & (BINSZ - 1)) << 18) | (unsigned)w;
                binbuf[bbs[bw] + r2] = ((unsigned)(w & (BINSZ - 1)) << 18) | (unsigned)u;
            }
        } else {
            for (int k = e; k < E && k < e + 4; ++k) {
                int u = tu[k];
                int w = NUSERS + ti[k];
                int bu = u >> BINSHIFT, bw = w >> BINSHIFT;
                int r1 = atomicAdd(&h[bu], 1);
                int r2 = atomicAdd(&h[bw], 1);
                binbuf[bbs[bu] + r1] = ((unsigned)(u & (BINSZ - 1)) << 18) | (unsigned)w;
                binbuf[bbs[bw] + r2] = ((unsigned)(w & (BINSZ - 1)) << 18) | (unsigned)u;
            }
        }
    }
}

// ---------------- stage 5: per-bin rank + adj fill (single writer per window) ----------------
// adj stores PRE-SHIFTED byte offsets (nbr * DIM * 2) so the gather does no scaling.
__global__ void bfill_kernel(const unsigned int* __restrict__ binbuf,
                             const int* __restrict__ binstart,
                             int* __restrict__ deg, int* __restrict__ adj) {
    __shared__ int c[BINSZ];
    int bin = blockIdx.x, t = threadIdx.x;     // blockDim = 512
    c[t] = 0;
    __syncthreads();
    int start = binstart[bin];
    int n = binstart[bin + 1] - start;
    int vbase = bin << BINSHIFT;
    for (int k = t; k < n; k += 512) {
        unsigned rec = binbuf[start + k];
        int vloc = rec >> 18;
        int nbr = (int)(rec & 0x3FFFFu);
        int r = atomicAdd(&c[vloc], 1);
        adj[((vbase + vloc) << 6) + r] = nbr << 7;   // byte offset of the row
    }
    __syncthreads();
    int v = vbase + t;
    if (v < NV) deg[v] = c[t];
}

// ---------------- init: Yh = f16( rsqrt(deg) ⊙ [users_w ; items_w] ) ----------------
// Also zeroes the pad row (row NV) of BOTH Yh and Dh (folds the 2 memsets).
__global__ void init_kernel(const float* __restrict__ users_w, const float* __restrict__ items_w,
                            const int* __restrict__ deg, _Float16* __restrict__ Yh,
                            _Float16* __restrict__ Dh) {
    int t = blockIdx.x * blockDim.x + threadIdx.x;   // one thread per 4 floats
    int n4 = NV * (DIM / 4);
    if (t >= n4) {
        int z = t - n4;                               // 32 zero-writers
        if (z < 16) reinterpret_cast<half4v*>(Yh + (size_t)NV * DIM)[z] = half4v{};
        else if (z < 32) reinterpret_cast<half4v*>(Dh + (size_t)NV * DIM)[z - 16] = half4v{};
        return;
    }
    int v = t >> 4;
    float r = rsqrtf(fmaxf((float)deg[v], 1.0f));
    const float4* src = (v < NUSERS)
        ? reinterpret_cast<const float4*>(users_w) + t
        : reinterpret_cast<const float4*>(items_w) + (t - NUSERS * (DIM / 4));
    float4 x = *src;
    half4v h;
    h.x = (_Float16)(x.x * r);
    h.y = (_Float16)(x.y * r);
    h.z = (_Float16)(x.z * r);
    h.w = (_Float16)(x.w * r);
    reinterpret_cast<half4v*>(Yh)[t] = h;
}

// ---------------- gather-reduce propagation ----------------
// One wave per vertex; lane = [slot g = lane>>3 | dim-octet p = lane&7].
// PAD=64 direct-slot CSR (adj = byte offsets): deg + adjacency line issue in one
// round; row-group loads gated by deg (>8, >16). First cross-slot reduce stage
// in packed f16 (deg<=32 path), stages 2-3 in f32. Zero row NV absorbs pads.
template <bool FINAL>
__global__ void gather_kernel(const _Float16* __restrict__ Yh, const int* __restrict__ deg,
                              const int* __restrict__ adj,
                              const float* __restrict__ beta_w,
                              void* __restrict__ dst_v, int layer) {
    int wid = (blockIdx.x * blockDim.x + threadIdx.x) >> 6;
    int lane = threadIdx.x & 63;
    if (wid >= NV) return;
    int g = lane >> 3;          // neighbor slot 0..7
    int p = lane & 7;           // dim octet: dims 8p..8p+7
    int s = wid << 6;
    const char* rowb = (const char*)Yh + p * 16;
    const int NVS = NV << 7;    // byte offset of the zero pad row

    // ---- round 1: everything independent issues together ----
    int dg = deg[wid];
    int raw0 = adj[s + g];
    int raw1 = adj[s + 8 + g];
    int raw2 = adj[s + 16 + g];
    int raw3 = adj[s + 24 + g];
    bool isU = wid < NUSERS;
    float bw_ = 0.f;
    half8v hy = {};
    if (isU && g == 0) {
        bw_ = beta_w[wid * NLAYERS + layer];
        hy = *reinterpret_cast<const half8v*>(Yh + (size_t)wid * DIM + p * 8);
    }

    // ---- round 2: row loads gated by degree (wave-uniform) ----
    int o0 = (g < dg) ? raw0 : NVS;
    half8v h0 = *reinterpret_cast<const half8v*>(rowb + (size_t)(unsigned)o0);

    float a[8];
    if (dg > 32) {
        // rare (~0.5%): full f32 path with tail, 3 f32 reduce stages
        int o1 = (8 + g  < dg) ? raw1 : NVS;
        int o2 = (16 + g < dg) ? raw2 : NVS;
        int o3 = (24 + g < dg) ? raw3 : NVS;
        half8v h1 = *reinterpret_cast<const half8v*>(rowb + (size_t)(unsigned)o1);
        half8v h2 = *reinterpret_cast<const half8v*>(rowb + (size_t)(unsigned)o2);
        half8v h3 = *reinterpret_cast<const half8v*>(rowb + (size_t)(unsigned)o3);
        half8v hs = (h0 + h1) + (h2 + h3);
#pragma unroll
        for (int j = 0; j < 8; ++j) a[j] = (float)hs[j];
#pragma unroll
        for (int jb = 0; jb < 4; ++jb) {
            int slotbase = 32 + jb * 8;
            if (slotbase < dg) {
                int ks = slotbase + g;
                int rw = adj[s + ks];
                int oj = (ks < dg) ? rw : NVS;
                half8v hj = *reinterpret_cast<const half8v*>(rowb + (size_t)(unsigned)oj);
#pragma unroll
                for (int j = 0; j < 8; ++j) a[j] += (float)hj[j];
            }
        }
#pragma unroll
        for (int j = 0; j < 8; ++j) a[j] += __shfl_xor(a[j], 8);
    } else {
        half8v hsum;
        if (dg > 16) {
            int o1 = (8 + g  < dg) ? raw1 : NVS;
            int o2 = (16 + g < dg) ? raw2 : NVS;
            int o3 = (24 + g < dg) ? raw3 : NVS;
            half8v h1 = *reinterpret_cast<const half8v*>(rowb + (size_t)(unsigned)o1);
            half8v h2 = *reinterpret_cast<const half8v*>(rowb + (size_t)(unsigned)o2);
            half8v h3 = *reinterpret_cast<const half8v*>(rowb + (size_t)(unsigned)o3);
            hsum = (h0 + h1) + (h2 + h3);
        } else if (dg > 8) {
            int o1 = (8 + g < dg) ? raw1 : NVS;
            half8v h1 = *reinterpret_cast<const half8v*>(rowb + (size_t)(unsigned)o1);
            hsum = h0 + h1;
        } else {
            hsum = h0;
        }
        // stage 1 (xor 8) in packed f16: 4 dword shfl + 4 pk_add
        union { half8v h; int i[4]; } u;
        u.h = hsum;
#pragma unroll
        for (int j = 0; j < 4; ++j) {
            int o = __shfl_xor(u.i[j], 8);
            half2v x = __builtin_bit_cast(half2v, u.i[j]);
            half2v y = __builtin_bit_cast(half2v, o);
            x = x + y;
            u.i[j] = __builtin_bit_cast(int, x);
        }
#pragma unroll
        for (int j = 0; j < 8; ++j) a[j] = (float)u.h[j];
    }

    // stages 2-3 in f32 (lane bits 4,5)
#pragma unroll
    for (int j = 0; j < 8; ++j) a[j] += __shfl_xor(a[j], 16);
#pragma unroll
    for (int j = 0; j < 8; ++j) a[j] += __shfl_xor(a[j], 32);

    if (g == 0) {                      // lanes 0..7 own the output row (octet p)
        float fdg = fmaxf((float)dg, 1.0f);
        float r = rsqrtf(fdg);
        float b = isU ? tanhf(bw_) : 0.f;
        if (!FINAL) {
            float rr = r * r;          // = 1/deg
            half8v o;
#pragma unroll
            for (int j = 0; j < 8; ++j) o[j] = (_Float16)(rr * a[j] + b * (float)hy[j]);
            reinterpret_cast<half8v*>((_Float16*)dst_v + (size_t)wid * DIM)[p] = o;
        } else {
            float c = b * __builtin_sqrtf(fdg);   // b / r
            float4 o0f, o1f;
            o0f.x = r * a[0] + c * (float)hy[0];
            o0f.y = r * a[1] + c * (float)hy[1];
            o0f.z = r * a[2] + c * (float)hy[2];
            o0f.w = r * a[3] + c * (float)hy[3];
            o1f.x = r * a[4] + c * (float)hy[4];
            o1f.y = r * a[5] + c * (float)hy[5];
            o1f.z = r * a[6] + c * (float)hy[6];
            o1f.w = r * a[7] + c * (float)hy[7];
            float4* dp = reinterpret_cast<float4*>((float*)dst_v + (size_t)wid * DIM + p * 8);
            dp[0] = o0f;
            dp[1] = o1f;
        }
    }
}

extern "C" void kernel_launch(void* const* d_in, const int* in_sizes, int n_in,
                              void* d_out, int out_size, void* d_ws, size_t ws_size,
                              hipStream_t stream) {
    const float* users_w = (const float*)d_in[0];
    const float* items_w = (const float*)d_in[1];
    const float* beta_w  = (const float*)d_in[2];
    const int*   tu      = (const int*)d_in[3];
    const int*   ti      = (const int*)d_in[4];
    const int    E       = in_sizes[3];
    float*       out     = (float*)d_out;

    int nblk = (E + EPB - 1) / EPB;

    // ---- workspace layout ----
    char* ws = (char*)d_ws;
    size_t woff = 0;
    auto take = [&](size_t bytes) {
        char* p = ws + woff;
        woff += (bytes + 1023) & ~(size_t)1023;
        return p;
    };
    int*      deg      = (int*)take((size_t)NV * sizeof(int));
    int*      cnt      = (int*)take((size_t)nblk * NBINS * sizeof(int));
    int*      bintot   = (int*)take((size_t)NBINS * sizeof(int));
    int*      binstart = (int*)take((size_t)(NBINS + 1) * sizeof(int));
    unsigned* binbuf   = (unsigned*)take((size_t)2 * E * sizeof(unsigned));
    int*      adj      = (int*)take((size_t)NV * PAD * sizeof(int));
    _Float16* Yh0      = (_Float16*)take((size_t)(NV + 1) * DIM * sizeof(_Float16));

    // f16 intermediate lives inside d_out (38.4 MB f32 holds 19.2 MB f16 + pad row)
    _Float16* Dh = (_Float16*)d_out;

    const int blk = 256;

    // ---- deterministic binned CSR build (zero global atomics) ----
    hist_kernel<<<nblk, 256, 0, stream>>>(tu, ti, cnt, E);
    colscan_kernel<<<NBINS, 256, 0, stream>>>(cnt, bintot, nblk);
    binscan_kernel<<<1, 512, 0, stream>>>(bintot, binstart);
    scatter_kernel<<<nblk, 256, 0, stream>>>(tu, ti, cnt, binstart, binbuf, E);
    bfill_kernel<<<NBINS, 512, 0, stream>>>(binbuf, binstart, deg, adj);

    // ---- init y-space f16 table (+ zero pad rows of Yh0 and Dh) ----
    int n4 = NV * (DIM / 4);
    init_kernel<<<(n4 + 32 + blk - 1) / blk, blk, 0, stream>>>(users_w, items_w, deg, Yh0, Dh);

    // ---- 3 propagation layers: Yh0 -> Dh(d_out) -> Yh0 -> out(f32) ----
    int gblocks = ((size_t)NV * 64 + blk - 1) / blk;

    gather_kernel<false><<<gblocks, blk, 0, stream>>>(Yh0, deg, adj, beta_w, Dh, 0);
    gather_kernel<false><<<gblocks, blk, 0, stream>>>(Dh, deg, adj, beta_w, Yh0, 1);
    gather_kernel<true ><<<gblocks, blk, 0, stream>>>(Yh0, deg, adj, beta_w, out, 2);
}